// Round 10
// baseline (70.774 us; speedup 1.0000x reference)
//
#include <hip/hip_runtime.h>
#include <hip/hip_bf16.h>

// y[b,i,j] = s[b,i] + s[b,j] - 2 * sum_k U[b,i,k]*U[b,j,k],  U = bf16(g^t * V)
//   (w*Vi*Vj = (g^t Vi)(g^t Vj), w = max(G,0)^(2t))  s[b,i] = sum_k U[b,i,k]^2
// bs=4, r=4096, d=64. Output 268 MB fp32 -> write-bandwidth bound.
// R9 -> R10: persistent pipelined blocks. Grid=256 (1 block/CU), each does
// 8 tiles: load frags(t+1) -> epilogue/stores(t) -> MFMA(t+1). Store stream
// is near-continuous; s_endpgm store-queue drain happens 256x not 2048x;
// next tile's loads hide under current tile's epilogue. Barriers stay
// lgkm-only so stores ride across them.

typedef __attribute__((ext_vector_type(8))) short bf16x8;   // 8 bf16 = 4 VGPRs
typedef __attribute__((ext_vector_type(4))) float f32x4;

constexpr int BS = 4, R = 4096, D = 64;
constexpr int LS = 260;       // LDS row stride (floats): 16B-aligned, worst 2-way conflict (free)
constexpr int TILES_X = 16;   // j blocks of 256
constexpr int TILES_Y = 32;   // i blocks of 128
constexpr int NTILES  = TILES_X * TILES_Y * BS;   // 2048
constexpr int NBLK    = 256;                      // 1 block/CU
constexpr int KITER   = NTILES / NBLK;            // 8 tiles per block

__device__ __forceinline__ void barrier_lds_only() {
    // order LDS ops, but let global (NT) stores stay in flight
    asm volatile("s_waitcnt lgkmcnt(0)" ::: "memory");
    __builtin_amdgcn_sched_barrier(0);
    __builtin_amdgcn_s_barrier();
    __builtin_amdgcn_sched_barrier(0);
}

// ---------------------------------------------------------------- prep ------
// One wave per row (64 lanes == d). Emits U = bf16(g^t * V), fp32 s = sum U^2.
__global__ __launch_bounds__(256) void prep_kernel(
    const float* __restrict__ G, const float* __restrict__ V,
    const float* __restrict__ wt,
    __hip_bfloat16* __restrict__ u_bf, float* __restrict__ s)
{
    int row  = blockIdx.x * 4 + (threadIdx.x >> 6);   // global row in [0, BS*R)
    int lane = threadIdx.x & 63;                       // k index (d == 64)
    if (row >= BS * R) return;
    int b = row / R;

    float t  = wt[0];
    float g  = fmaxf(G[b * D + lane], 0.0f);
    float sw = powf(g, t);                             // g^t; 0^0==1 matches jnp
    float u  = sw * V[(size_t)row * D + lane];

    __hip_bfloat16 ub = __float2bfloat16(u);
    u_bf[(size_t)row * D + lane] = ub;

    // s from the same bf16-rounded values -> diagonal cancels vs MFMA cross
    float uf   = __bfloat162float(ub);
    float prod = uf * uf;
    #pragma unroll
    for (int off = 32; off; off >>= 1) prod += __shfl_down(prod, off);
    if (lane == 0) s[row] = prod;
}

// ---------------------------------------------------------------- dist ------
// Block: 512 threads = 8 waves, arranged 2 (i) x 4 (j); wave tile 64x64;
// block tile 128 (i) x 256 (j). Persistent: block bid does tiles
// bid + k*256, k=0..7 (tile id = x + 16*y + 512*z; j fastest within a
// generation -> contiguous write window per instant).
// MFMA 16x16x32 bf16 layouts (HW-verified, learn_hip m89/m91/m97):
//   A: lane holds A[row=l&15][k=(l>>4)*8 + 0..7]   (contiguous 16B)
//   B: lane holds B[k=(l>>4)*8 + 0..7][col=l&15] == U[j+(l&15)][k...] for B=U^T
//   C/D: col = l&15, row = (l>>4)*4 + reg
__global__ __launch_bounds__(512) void dist_kernel(
    const short* __restrict__ U, const float* __restrict__ s,
    float* __restrict__ out)
{
    __shared__ float lds[64 * LS];   // 66.5 KB

    int lane = threadIdx.x & 63;
    int wave = threadIdx.x >> 6;     // 0..7
    int wr   = wave >> 2;            // 0..1  (i half)
    int wc   = wave & 3;             // 0..3  (j quarter)
    int lrow = lane & 15;
    int kgrp = lane >> 4;            // 0..3
    int bid  = blockIdx.x;

    bf16x8 a[4][2];   // A frags: 4 row-blocks x 2 K-steps
    bf16x8 bf[4][2];  // B frags: 4 jt x 2 K-steps
    f32x4  acc[4][4];

    auto load_frags = [&](int tid) {
        int x = tid & (TILES_X - 1);
        int y = (tid >> 4) & (TILES_Y - 1);
        int z = tid >> 9;
        const short* Ap = U + ((size_t)z * R + y * 128 + wr * 64) * D;
        const short* Bp = U + ((size_t)z * R + x * 256 + wc * 64) * D;
        #pragma unroll
        for (int rb = 0; rb < 4; ++rb)
            #pragma unroll
            for (int ks = 0; ks < 2; ++ks)
                a[rb][ks] = *(const bf16x8*)(Ap + (rb * 16 + lrow) * D + ks * 32 + kgrp * 8);
        #pragma unroll
        for (int jt = 0; jt < 4; ++jt)
            #pragma unroll
            for (int ks = 0; ks < 2; ++ks)
                bf[jt][ks] = *(const bf16x8*)(Bp + (jt * 16 + lrow) * D + ks * 32 + kgrp * 8);
    };

    auto mfma_all = [&]() {
        #pragma unroll
        for (int rb = 0; rb < 4; ++rb)
            #pragma unroll
            for (int jt = 0; jt < 4; ++jt)
                acc[rb][jt] = f32x4{0.f, 0.f, 0.f, 0.f};
        #pragma unroll
        for (int jt = 0; jt < 4; ++jt)
            #pragma unroll
            for (int rb = 0; rb < 4; ++rb) {
                acc[rb][jt] = __builtin_amdgcn_mfma_f32_16x16x32_bf16(a[rb][0], bf[jt][0], acc[rb][jt], 0, 0, 0);
                acc[rb][jt] = __builtin_amdgcn_mfma_f32_16x16x32_bf16(a[rb][1], bf[jt][1], acc[rb][jt], 0, 0, 0);
            }
    };

    // pipeline prologue: tile 0 loaded + computed
    load_frags(bid);
    mfma_all();

    for (int k = 0; k < KITER; ++k) {
        int tid = bid + k * NBLK;
        int x = tid & (TILES_X - 1);
        int y = (tid >> 4) & (TILES_Y - 1);
        int z = tid >> 9;

        // prefetch next tile's fragments; loads stay in flight under the
        // epilogue (compiler waits vmcnt before next mfma_all's use).
        if (k + 1 < KITER) load_frags(bid + (k + 1) * NBLK);

        const float* sb = s + (size_t)z * R;
        float si_lane = sb[y * 128 + wr * 64 + lane];
        float* outb = out + ((size_t)z * R + y * 128) * R + x * 256;

        #pragma unroll
        for (int c = 0; c < 2; ++c) {
            if (wr == c) {
                #pragma unroll
                for (int rb = 0; rb < 4; ++rb) {
                    #pragma unroll
                    for (int rg = 0; rg < 4; ++rg) {
                        int rl = rb * 16 + kgrp * 4 + rg;          // 0..63 local row
                        float si = __shfl(si_lane, rl);
                        #pragma unroll
                        for (int jt = 0; jt < 4; ++jt) {
                            float sj = sb[x * 256 + wc * 64 + jt * 16 + lrow];
                            float y_ = si + sj - 2.0f * acc[rb][jt][rg];
                            lds[rl * LS + wc * 64 + jt * 16 + lrow] = y_;
                        }
                    }
                }
            }
            barrier_lds_only();   // ds_writes visible; global stores NOT drained

            // all 8 waves store chunk c: wave w -> rows w*8..w*8+7.
            // Each instruction: 64 lanes x 16B = one contiguous 1KB segment.
            #pragma unroll
            for (int r = 0; r < 8; ++r) {
                int rl = wave * 8 + r;
                f32x4 v = *(const f32x4*)&lds[rl * LS + lane * 4];
                __builtin_nontemporal_store(v,
                    (f32x4*)(outb + (size_t)(c * 64 + rl) * R + lane * 4));
            }
            barrier_lds_only();   // ds_reads done -> LDS reusable next chunk/tile
        }

        // compute next tile while this tile's stores retire
        if (k + 1 < KITER) mfma_all();
    }
}

// --------------------------------------------------------------------------
extern "C" void kernel_launch(void* const* d_in, const int* in_sizes, int n_in,
                              void* d_out, int out_size, void* d_ws, size_t ws_size,
                              hipStream_t stream) {
    const float* G  = (const float*)d_in[0];
    const float* V  = (const float*)d_in[1];
    const float* wt = (const float*)d_in[2];
    float* out = (float*)d_out;

    char* ws = (char*)d_ws;
    __hip_bfloat16* u_bf = (__hip_bfloat16*)ws;                             // 2 MB
    float*          s    = (float*)        (ws + (size_t)BS * R * D * 2);   // 64 KB

    prep_kernel<<<BS * R / 4, 256, 0, stream>>>(G, V, wt, u_bf, s);

    dist_kernel<<<NBLK, 512, 0, stream>>>((const short*)u_bf, s, out);
}